// Round 4
// baseline (469.391 us; speedup 1.0000x reference)
//
#include <hip/hip_runtime.h>
#include <hip/hip_bf16.h>

// Problem constants (fixed by the reference)
#define NB 16     // batch N
#define TT 1024   // L == M
#define CC 512    // IN_DIM == PARAM_DIM
#define PP 512    // PLANES
#define GG 4      // GROUPS
#define DD 128    // GROUP_PLANES
#define OO 2048   // OUT_DIM

#define SCL 0.04419417382415922f  // 1/sqrt(512): equal_linear scale AND attn scale

typedef __attribute__((ext_vector_type(8))) short short8;   // 8 bf16 (4 VGPRs)
typedef __attribute__((ext_vector_type(4))) float floatx4;  // 4 fp32 acc
#define MFMA(a, b, c) __builtin_amdgcn_mfma_f32_16x16x32_bf16((a), (b), (c), 0, 0, 0)

static __device__ __forceinline__ float bf2f(unsigned short u) {
  union { unsigned int i; float f; } v; v.i = ((unsigned int)u) << 16; return v.f;
}
// HW conversion: compiles to v_cvt_pk_bf16_f32 (RNE, 2 elems/instr) — the
// manual bit-round version was ~4 VALU/element and made staging VALU-bound.
static __device__ __forceinline__ unsigned short f2bf(float f) {
  __hip_bfloat16 h = __float2bfloat16(f);
  return *reinterpret_cast<unsigned short*>(&h);
}
static __device__ __forceinline__ ushort4 pack4(float4 v) {
  ushort4 o; o.x = f2bf(v.x); o.y = f2bf(v.y); o.z = f2bf(v.z); o.w = f2bf(v.w); return o;
}

// ---------------------------------------------------------------------------
// k_proj<VLAY>: D[p][t] = SCL * (w[p][:] . x[n][t][:]) + b[p]
//   (used for Q only now; K/V are fused in k_projkv)
//   VLAY==0: y[n][t][PP]  (d-contiguous for QK^T operands)
// 128x128 block tile, 4 waves (2x2), wave 64x64 = 4x4 MFMA tiles, BK=32.
// ---------------------------------------------------------------------------
template <int VLAY>
__global__ __launch_bounds__(256) void k_proj(
    const float* __restrict__ x, const float* __restrict__ w,
    const float* __restrict__ b, unsigned short* __restrict__ y) {
  __shared__ unsigned short Aw[128][32];  // [p][k] bf16
  __shared__ unsigned short Xw[128][32];  // [t][k] bf16
  const int n  = blockIdx.z;
  const int p0 = blockIdx.y * 128;
  const int t0 = blockIdx.x * 128;
  const int tid  = threadIdx.x;
  const int wave = tid >> 6, lane = tid & 63;
  const int l15  = lane & 15, quad = lane >> 4;
  const int wm = (wave >> 1) * 64, wn = (wave & 1) * 64;
  const int srow = tid >> 3, scol = (tid & 7) * 4;  // staging: 8 thr/row of 32
  const float* xn = x + (size_t)n * TT * CC;
  floatx4 acc[4][4] = {};

  for (int k0 = 0; k0 < CC; k0 += 32) {
    float4 aw[4], ax[4];
#pragma unroll
    for (int q = 0; q < 4; ++q) {
      aw[q] = *reinterpret_cast<const float4*>(w  + (size_t)(p0 + srow + q * 32) * CC + k0 + scol);
      ax[q] = *reinterpret_cast<const float4*>(xn + (size_t)(t0 + srow + q * 32) * CC + k0 + scol);
    }
    __syncthreads();  // previous tile consumed
#pragma unroll
    for (int q = 0; q < 4; ++q) {
      *reinterpret_cast<ushort4*>(&Aw[srow + q * 32][scol]) = pack4(aw[q]);
      *reinterpret_cast<ushort4*>(&Xw[srow + q * 32][scol]) = pack4(ax[q]);
    }
    __syncthreads();
    short8 af[4], bx[4];
#pragma unroll
    for (int mt = 0; mt < 4; ++mt)
      af[mt] = *reinterpret_cast<const short8*>(&Aw[wm + mt * 16 + l15][quad * 8]);
#pragma unroll
    for (int nt = 0; nt < 4; ++nt)
      bx[nt] = *reinterpret_cast<const short8*>(&Xw[wn + nt * 16 + l15][quad * 8]);
#pragma unroll
    for (int mt = 0; mt < 4; ++mt)
#pragma unroll
      for (int nt = 0; nt < 4; ++nt)
        acc[mt][nt] = MFMA(af[mt], bx[nt], acc[mt][nt]);
  }

#pragma unroll
  for (int mt = 0; mt < 4; ++mt) {
    const int pb = p0 + wm + mt * 16 + quad * 4;  // 4 consecutive p rows
    const float4 bias = *reinterpret_cast<const float4*>(b + pb);
    const float bb[4] = {bias.x, bias.y, bias.z, bias.w};
#pragma unroll
    for (int nt = 0; nt < 4; ++nt) {
      const int tc = t0 + wn + nt * 16 + l15;  // column t
      if (VLAY == 0) {
        ushort4 o;
        o.x = f2bf(acc[mt][nt][0] * SCL + bb[0]);
        o.y = f2bf(acc[mt][nt][1] * SCL + bb[1]);
        o.z = f2bf(acc[mt][nt][2] * SCL + bb[2]);
        o.w = f2bf(acc[mt][nt][3] * SCL + bb[3]);
        *reinterpret_cast<ushort4*>(y + ((size_t)n * TT + tc) * PP + pb) = o;
      } else {
#pragma unroll
        for (int r = 0; r < 4; ++r)
          y[((size_t)n * PP + pb + r) * TT + tc] = f2bf(acc[mt][nt][r] * SCL + bb[r]);
      }
    }
  }
}

// ---------------------------------------------------------------------------
// k_projkv: fused K-proj + V-proj. Both read the SAME x tile (attention);
// stage it once, stage both weight tiles, 32 MFMAs per K-step (2x compute
// density per barrier vs separate kernels, one fewer 32 MB x read).
//   K out: yk[n][t][PP]  (VLAY0)   V out: yv[n][PP][t]  (VLAY1)
// ---------------------------------------------------------------------------
__global__ __launch_bounds__(256) void k_projkv(
    const float* __restrict__ x,
    const float* __restrict__ kw, const float* __restrict__ kb,
    const float* __restrict__ vw, const float* __restrict__ vb,
    unsigned short* __restrict__ yk, unsigned short* __restrict__ yv) {
  __shared__ unsigned short Ak[128][32];  // [p][k] bf16 (k_w)
  __shared__ unsigned short Av[128][32];  // [p][k] bf16 (v_w)
  __shared__ unsigned short Xw[128][32];  // [t][k] bf16
  const int n  = blockIdx.z;
  const int p0 = blockIdx.y * 128;
  const int t0 = blockIdx.x * 128;
  const int tid  = threadIdx.x;
  const int wave = tid >> 6, lane = tid & 63;
  const int l15  = lane & 15, quad = lane >> 4;
  const int wm = (wave >> 1) * 64, wn = (wave & 1) * 64;
  const int srow = tid >> 3, scol = (tid & 7) * 4;
  const float* xn = x + (size_t)n * TT * CC;
  floatx4 ack[4][4] = {};
  floatx4 acv[4][4] = {};

  for (int k0 = 0; k0 < CC; k0 += 32) {
    float4 a1[4], a2[4], ax[4];
#pragma unroll
    for (int q = 0; q < 4; ++q) {
      a1[q] = *reinterpret_cast<const float4*>(kw + (size_t)(p0 + srow + q * 32) * CC + k0 + scol);
      a2[q] = *reinterpret_cast<const float4*>(vw + (size_t)(p0 + srow + q * 32) * CC + k0 + scol);
      ax[q] = *reinterpret_cast<const float4*>(xn + (size_t)(t0 + srow + q * 32) * CC + k0 + scol);
    }
    __syncthreads();
#pragma unroll
    for (int q = 0; q < 4; ++q) {
      *reinterpret_cast<ushort4*>(&Ak[srow + q * 32][scol]) = pack4(a1[q]);
      *reinterpret_cast<ushort4*>(&Av[srow + q * 32][scol]) = pack4(a2[q]);
      *reinterpret_cast<ushort4*>(&Xw[srow + q * 32][scol]) = pack4(ax[q]);
    }
    __syncthreads();
    short8 afk[4], afv[4], bx[4];
#pragma unroll
    for (int mt = 0; mt < 4; ++mt) {
      afk[mt] = *reinterpret_cast<const short8*>(&Ak[wm + mt * 16 + l15][quad * 8]);
      afv[mt] = *reinterpret_cast<const short8*>(&Av[wm + mt * 16 + l15][quad * 8]);
    }
#pragma unroll
    for (int nt = 0; nt < 4; ++nt)
      bx[nt] = *reinterpret_cast<const short8*>(&Xw[wn + nt * 16 + l15][quad * 8]);
#pragma unroll
    for (int mt = 0; mt < 4; ++mt)
#pragma unroll
      for (int nt = 0; nt < 4; ++nt) {
        ack[mt][nt] = MFMA(afk[mt], bx[nt], ack[mt][nt]);
        acv[mt][nt] = MFMA(afv[mt], bx[nt], acv[mt][nt]);
      }
  }

#pragma unroll
  for (int mt = 0; mt < 4; ++mt) {
    const int pb = p0 + wm + mt * 16 + quad * 4;
    const float4 biask = *reinterpret_cast<const float4*>(kb + pb);
    const float4 biasv = *reinterpret_cast<const float4*>(vb + pb);
    const float bk_[4] = {biask.x, biask.y, biask.z, biask.w};
    const float bv_[4] = {biasv.x, biasv.y, biasv.z, biasv.w};
#pragma unroll
    for (int nt = 0; nt < 4; ++nt) {
      const int tc = t0 + wn + nt * 16 + l15;
      // K: [n][t][PP]
      ushort4 o;
      o.x = f2bf(ack[mt][nt][0] * SCL + bk_[0]);
      o.y = f2bf(ack[mt][nt][1] * SCL + bk_[1]);
      o.z = f2bf(ack[mt][nt][2] * SCL + bk_[2]);
      o.w = f2bf(ack[mt][nt][3] * SCL + bk_[3]);
      *reinterpret_cast<ushort4*>(yk + ((size_t)n * TT + tc) * PP + pb) = o;
      // V: [n][PP][t]
#pragma unroll
      for (int r = 0; r < 4; ++r)
        yv[((size_t)n * PP + pb + r) * TT + tc] = f2bf(acv[mt][nt][r] * SCL + bv_[r]);
    }
  }
}

// ---------------------------------------------------------------------------
// k_attn: one block per (n, g, 32 m-rows). MFMA QK^T -> LDS scores ->
// exact softmax -> MFMA AV. Q,K: [n][t][PP]; V: [n][p][TT]; SV: [n][t][PP].
// Flat 2048-block grid with XCD-chunked swizzle: XCD k (lin%8==k) owns
// work-units [k*256,(k+1)*256) = 8 complete (n,g) pairs, so each 256 KB
// K/V slice is fetched into exactly ONE per-XCD L2 and all 32 consumer
// blocks hit L2 (proven round 3: FETCH 139 MB -> 24.7 MB, -25 us).
// ---------------------------------------------------------------------------
__global__ __launch_bounds__(256) void k_attn(
    const unsigned short* __restrict__ Q,
    const unsigned short* __restrict__ K,
    const unsigned short* __restrict__ V,
    unsigned short* __restrict__ SV) {
  __shared__ unsigned short Sc[32][1032];  // bf16 scores, row pad 8 (16B-aligned rows)
  __shared__ float rowinv[32];
  const int lin = blockIdx.x;
  const int wu  = (lin >> 3) | ((lin & 7) << 8);  // bijective: 2048 = 8 * 256
  const int m0 = (wu & 31) * 32;
  const int g  = (wu >> 5) & 3;
  const int n  = wu >> 7;
  const int tid  = threadIdx.x;
  const int wave = tid >> 6, lane = tid & 63;
  const int l15  = lane & 15, quad = lane >> 4;

  const unsigned short* Qn = Q + (size_t)n * TT * PP;
  const unsigned short* Kn = K + (size_t)n * TT * PP;
  const unsigned short* Vn = V + ((size_t)n * PP + g * DD) * TT;

  // Q a-frags: 2 m-tiles x 4 d-steps, resident across passes (32m x 128d)
  short8 aq[2][4];
#pragma unroll
  for (int mt = 0; mt < 2; ++mt)
#pragma unroll
    for (int ds = 0; ds < 4; ++ds)
      aq[mt][ds] = *reinterpret_cast<const short8*>(
          Qn + (size_t)(m0 + mt * 16 + l15) * PP + g * DD + ds * 32 + quad * 8);

  // ---- QK^T: 4 passes of 256 l; wave covers 4 l-tiles of 16 ----
#pragma unroll
  for (int pass = 0; pass < 4; ++pass) {
    // Batch all 16 K-frag loads of this pass (64 VGPRs in flight).
    short8 bk[4][4];
#pragma unroll
    for (int ds = 0; ds < 4; ++ds)
#pragma unroll
      for (int j = 0; j < 4; ++j)
        bk[ds][j] = *reinterpret_cast<const short8*>(
            Kn + (size_t)(pass * 256 + (wave * 4 + j) * 16 + l15) * PP +
            g * DD + ds * 32 + quad * 8);
    floatx4 acc[2][4] = {};
#pragma unroll
    for (int ds = 0; ds < 4; ++ds)
#pragma unroll
      for (int j = 0; j < 4; ++j) {
        acc[0][j] = MFMA(aq[0][ds], bk[ds][j], acc[0][j]);
        acc[1][j] = MFMA(aq[1][ds], bk[ds][j], acc[1][j]);
      }
#pragma unroll
    for (int mt = 0; mt < 2; ++mt)
#pragma unroll
      for (int j = 0; j < 4; ++j) {
        const int lc = pass * 256 + (wave * 4 + j) * 16 + l15;
#pragma unroll
        for (int r = 0; r < 4; ++r)
          Sc[mt * 16 + quad * 4 + r][lc] = f2bf(acc[mt][j][r] * SCL);
      }
  }
  __syncthreads();

  // ---- exact softmax: 8 lanes per row, INTERLEAVED 16B chunks ----
  // lane j, iter i owns chunk (i*8+j): an 8-lane row-group covers 128
  // contiguous bytes per iter -> every bank hit exactly the hw minimum.
  {
    const int mi = tid >> 3;
    const int j  = tid & 7;
    unsigned short* row = &Sc[mi][0];
    float mx = -1e30f;
#pragma unroll
    for (int i = 0; i < 16; ++i) {
      short8 u = *reinterpret_cast<const short8*>(&row[(i * 8 + j) * 8]);
      float a0 = fmaxf(bf2f((unsigned short)u[0]), bf2f((unsigned short)u[1]));
      float a1 = fmaxf(bf2f((unsigned short)u[2]), bf2f((unsigned short)u[3]));
      float a2 = fmaxf(bf2f((unsigned short)u[4]), bf2f((unsigned short)u[5]));
      float a3 = fmaxf(bf2f((unsigned short)u[6]), bf2f((unsigned short)u[7]));
      mx = fmaxf(mx, fmaxf(fmaxf(a0, a1), fmaxf(a2, a3)));
    }
#pragma unroll
    for (int off = 4; off; off >>= 1) mx = fmaxf(mx, __shfl_xor(mx, off, 8));
    float sum = 0.f;
#pragma unroll
    for (int i = 0; i < 16; ++i) {
      short8 u = *reinterpret_cast<short8*>(&row[(i * 8 + j) * 8]);
      short8 o;
      float s0 = 0.f, s1 = 0.f;
#pragma unroll
      for (int e = 0; e < 8; e += 2) {
        float e0 = __expf(bf2f((unsigned short)u[e])     - mx);
        float e1 = __expf(bf2f((unsigned short)u[e + 1]) - mx);
        s0 += e0; s1 += e1;
        o[e]     = (short)f2bf(e0);
        o[e + 1] = (short)f2bf(e1);
      }
      sum += s0 + s1;
      *reinterpret_cast<short8*>(&row[(i * 8 + j) * 8]) = o;
    }
#pragma unroll
    for (int off = 4; off; off >>= 1) sum += __shfl_xor(sum, off, 8);
    if (j == 0) rowinv[mi] = 1.f / sum;
  }
  __syncthreads();

  // ---- AV: wave owns 32 d (2 d-tiles) x 32 m (2 m-tiles); 1024 l in steps of 32 ----
  floatx4 av[2][2] = {};  // [d-tile][m-tile]
#pragma unroll 4
  for (int ls = 0; ls < 32; ++ls) {
    short8 va[2], bp[2];
#pragma unroll
    for (int a = 0; a < 2; ++a)
      va[a] = *reinterpret_cast<const short8*>(
          Vn + (size_t)(wave * 32 + a * 16 + l15) * TT + ls * 32 + quad * 8);
#pragma unroll
    for (int mt = 0; mt < 2; ++mt)
      bp[mt] = *reinterpret_cast<const short8*>(&Sc[mt * 16 + l15][ls * 32 + quad * 8]);
#pragma unroll
    for (int a = 0; a < 2; ++a)
#pragma unroll
      for (int mt = 0; mt < 2; ++mt)
        av[a][mt] = MFMA(va[a], bp[mt], av[a][mt]);
  }
#pragma unroll
  for (int a = 0; a < 2; ++a) {
    const int pb = g * DD + wave * 32 + a * 16 + quad * 4;  // 4 consecutive planes
#pragma unroll
    for (int mt = 0; mt < 2; ++mt) {
      const float inv = rowinv[mt * 16 + l15];  // D cols = m
      ushort4 o;
      o.x = f2bf(av[a][mt][0] * inv);
      o.y = f2bf(av[a][mt][1] * inv);
      o.z = f2bf(av[a][mt][2] * inv);
      o.w = f2bf(av[a][mt][3] * inv);
      *reinterpret_cast<ushort4*>(
          SV + ((size_t)n * TT + m0 + mt * 16 + l15) * PP + pb) = o;
    }
  }
}

// ---------------------------------------------------------------------------
// k_out: out[n][t][o] = SCL * sum_p SV[t][p] * w[o][p] + b[o]   (fp32 out)
//   A = proj_w (OO x PP fp32), B = SV (TT x PP bf16, p-contiguous).
// 128(o) x 128(t) tile, same skeleton as k_proj.
// (Round-3 XCD swizzle REVERTED: its per-XCD working set proj_w 4MB +
//  SV-slice 2MB > 4MB L2 -> thrash, -30us regression. Plain grid restored.)
// ---------------------------------------------------------------------------
__global__ __launch_bounds__(256) void k_out(
    const unsigned short* __restrict__ SVp, const float* __restrict__ w,
    const float* __restrict__ b, float* __restrict__ out) {
  __shared__ unsigned short Wt[128][32];  // [o][p] bf16
  __shared__ unsigned short St[128][32];  // [t][p] bf16
  const int n  = blockIdx.z;
  const int o0 = blockIdx.y * 128;
  const int t0 = blockIdx.x * 128;
  const int tid  = threadIdx.x;
  const int wave = tid >> 6, lane = tid & 63;
  const int l15  = lane & 15, quad = lane >> 4;
  const int wm = (wave >> 1) * 64, wn = (wave & 1) * 64;
  const int srow = tid >> 3, scol = (tid & 7) * 4;
  const unsigned short* SVn = SVp + (size_t)n * TT * PP;
  floatx4 acc[4][4] = {};

  for (int k0 = 0; k0 < PP; k0 += 32) {
    float4 awf[4];
    ushort4 us[4];
#pragma unroll
    for (int q = 0; q < 4; ++q) {
      awf[q] = *reinterpret_cast<const float4*>(w + (size_t)(o0 + srow + q * 32) * PP + k0 + scol);
      us[q]  = *reinterpret_cast<const ushort4*>(SVn + (size_t)(t0 + srow + q * 32) * PP + k0 + scol);
    }
    __syncthreads();
#pragma unroll
    for (int q = 0; q < 4; ++q) {
      *reinterpret_cast<ushort4*>(&Wt[srow + q * 32][scol]) = pack4(awf[q]);
      *reinterpret_cast<ushort4*>(&St[srow + q * 32][scol]) = us[q];
    }
    __syncthreads();
    short8 af[4], bs[4];
#pragma unroll
    for (int mt = 0; mt < 4; ++mt)
      af[mt] = *reinterpret_cast<const short8*>(&Wt[wm + mt * 16 + l15][quad * 8]);
#pragma unroll
    for (int nt = 0; nt < 4; ++nt)
      bs[nt] = *reinterpret_cast<const short8*>(&St[wn + nt * 16 + l15][quad * 8]);
#pragma unroll
    for (int mt = 0; mt < 4; ++mt)
#pragma unroll
      for (int nt = 0; nt < 4; ++nt)
        acc[mt][nt] = MFMA(af[mt], bs[nt], acc[mt][nt]);
  }

#pragma unroll
  for (int mt = 0; mt < 4; ++mt) {
    const int ob = o0 + wm + mt * 16 + quad * 4;  // 4 consecutive o
    const float4 bias = *reinterpret_cast<const float4*>(b + ob);
    const float bb[4] = {bias.x, bias.y, bias.z, bias.w};
#pragma unroll
    for (int nt = 0; nt < 4; ++nt) {
      const int tc = t0 + wn + nt * 16 + l15;
      float4 o;
      o.x = acc[mt][nt][0] * SCL + bb[0];
      o.y = acc[mt][nt][1] * SCL + bb[1];
      o.z = acc[mt][nt][2] * SCL + bb[2];
      o.w = acc[mt][nt][3] * SCL + bb[3];
      *reinterpret_cast<float4*>(out + ((size_t)n * TT + tc) * OO + ob) = o;
    }
  }
}

// ---------------------------------------------------------------------------
// Buffers: inputs/outputs are fp32 (proven round 3). d_out is 128 MB fp32;
// Q/K/V bf16 scratch (16 MB each) live at its head and are dead before k_out
// writes. SV (16 MB bf16) lives in d_ws (survives while out is written).
// ---------------------------------------------------------------------------
extern "C" void kernel_launch(void* const* d_in, const int* in_sizes, int n_in,
                              void* d_out, int out_size, void* d_ws, size_t ws_size,
                              hipStream_t stream) {
  (void)in_sizes; (void)n_in; (void)out_size; (void)ws_size;
  const float* attention = (const float*)d_in[0];  // (16,1024,512)
  const float* op_param  = (const float*)d_in[1];  // (16,1024,512)
  const float* q_w = (const float*)d_in[2];        // (512,512)
  const float* q_b = (const float*)d_in[3];        // (512)
  const float* k_w = (const float*)d_in[4];
  const float* k_b = (const float*)d_in[5];
  const float* v_w = (const float*)d_in[6];
  const float* v_b = (const float*)d_in[7];
  const float* proj_w = (const float*)d_in[8];     // (2048,512)
  const float* proj_b = (const float*)d_in[9];     // (2048)
  float* out = (float*)d_out;                      // (16,1024,2048) fp32 = 128 MB

  const size_t NPT = (size_t)NB * PP * TT;         // 8,388,608 elems = 16 MB bf16
  unsigned short* scratch = (unsigned short*)d_out;
  unsigned short* Qw  = scratch;            // [n][t][PP]
  unsigned short* Kw  = scratch + NPT;      // [n][t][PP]
  unsigned short* Vw  = scratch + 2 * NPT;  // [n][p][TT]
  unsigned short* SVw = (unsigned short*)d_ws;  // [n][t][PP]

  dim3 blk(256);
  dim3 gp(TT / 128, PP / 128, NB);                 // (8, 4, 16)
  k_proj<0><<<gp, blk, 0, stream>>>(op_param, q_w, q_b, Qw);
  k_projkv<<<gp, blk, 0, stream>>>(attention, k_w, k_b, v_w, v_b, Kw, Vw);
  k_attn<<<dim3(2048), blk, 0, stream>>>(Qw, Kw, Vw, SVw);              // XCD-chunked
  k_out<<<dim3(TT / 128, OO / 128, NB), blk, 0, stream>>>(SVw, proj_w, proj_b, out);
}

// Round 5
// 447.052 us; speedup vs baseline: 1.0500x; 1.0500x over previous
//
#include <hip/hip_runtime.h>
#include <hip/hip_bf16.h>

// Problem constants (fixed by the reference)
#define NB 16     // batch N
#define TT 1024   // L == M
#define CC 512    // IN_DIM == PARAM_DIM
#define PP 512    // PLANES
#define GG 4      // GROUPS
#define DD 128    // GROUP_PLANES
#define OO 2048   // OUT_DIM

#define SCL 0.04419417382415922f  // 1/sqrt(512): equal_linear scale AND attn scale

typedef __attribute__((ext_vector_type(8))) short short8;   // 8 bf16 (4 VGPRs)
typedef __attribute__((ext_vector_type(4))) float floatx4;  // 4 fp32 acc
#define MFMA(a, b, c) __builtin_amdgcn_mfma_f32_16x16x32_bf16((a), (b), (c), 0, 0, 0)

static __device__ __forceinline__ float bf2f(unsigned short u) {
  union { unsigned int i; float f; } v; v.i = ((unsigned int)u) << 16; return v.f;
}
// HW conversion (v_cvt path). If round-5 non-attn stays ~326us instead of
// ~280, THIS is the R4 regressor -> revert to manual bit-round next.
static __device__ __forceinline__ unsigned short f2bf(float f) {
  __hip_bfloat16 h = __float2bfloat16(f);
  return *reinterpret_cast<unsigned short*>(&h);
}
static __device__ __forceinline__ ushort4 pack4(float4 v) {
  ushort4 o; o.x = f2bf(v.x); o.y = f2bf(v.y); o.z = f2bf(v.z); o.w = f2bf(v.w); return o;
}

// ---------------------------------------------------------------------------
// k_proj<VLAY>: D[p][t] = SCL * (w[p][:] . x[n][t][:]) + b[p]
//   A = w (PP x CC fp32), B = x (TT x CC fp32 per n) — both k-contiguous.
//   VLAY==0: y[n][t][PP]  (Q/K: d-contiguous for QK^T operands)
//   VLAY==1: y[n][PP][t]  (V: l-contiguous for AV A-operand)
// 128x128 block tile, 4 waves (2x2), wave 64x64 = 4x4 MFMA tiles, BK=32.
// (R4's K/V fusion REVERTED: bundled-change regression, suspected VGPR
//  pressure/spill in the 2-acc variant. This is the R2-verified shape.)
// ---------------------------------------------------------------------------
template <int VLAY>
__global__ __launch_bounds__(256) void k_proj(
    const float* __restrict__ x, const float* __restrict__ w,
    const float* __restrict__ b, unsigned short* __restrict__ y) {
  __shared__ unsigned short Aw[128][32];  // [p][k] bf16
  __shared__ unsigned short Xw[128][32];  // [t][k] bf16
  const int n  = blockIdx.z;
  const int p0 = blockIdx.y * 128;
  const int t0 = blockIdx.x * 128;
  const int tid  = threadIdx.x;
  const int wave = tid >> 6, lane = tid & 63;
  const int l15  = lane & 15, quad = lane >> 4;
  const int wm = (wave >> 1) * 64, wn = (wave & 1) * 64;
  const int srow = tid >> 3, scol = (tid & 7) * 4;  // staging: 8 thr/row of 32
  const float* xn = x + (size_t)n * TT * CC;
  floatx4 acc[4][4] = {};

  for (int k0 = 0; k0 < CC; k0 += 32) {
    float4 aw[4], ax[4];
#pragma unroll
    for (int q = 0; q < 4; ++q) {
      aw[q] = *reinterpret_cast<const float4*>(w  + (size_t)(p0 + srow + q * 32) * CC + k0 + scol);
      ax[q] = *reinterpret_cast<const float4*>(xn + (size_t)(t0 + srow + q * 32) * CC + k0 + scol);
    }
    __syncthreads();  // previous tile consumed
#pragma unroll
    for (int q = 0; q < 4; ++q) {
      *reinterpret_cast<ushort4*>(&Aw[srow + q * 32][scol]) = pack4(aw[q]);
      *reinterpret_cast<ushort4*>(&Xw[srow + q * 32][scol]) = pack4(ax[q]);
    }
    __syncthreads();
    short8 af[4], bx[4];
#pragma unroll
    for (int mt = 0; mt < 4; ++mt)
      af[mt] = *reinterpret_cast<const short8*>(&Aw[wm + mt * 16 + l15][quad * 8]);
#pragma unroll
    for (int nt = 0; nt < 4; ++nt)
      bx[nt] = *reinterpret_cast<const short8*>(&Xw[wn + nt * 16 + l15][quad * 8]);
#pragma unroll
    for (int mt = 0; mt < 4; ++mt)
#pragma unroll
      for (int nt = 0; nt < 4; ++nt)
        acc[mt][nt] = MFMA(af[mt], bx[nt], acc[mt][nt]);
  }

#pragma unroll
  for (int mt = 0; mt < 4; ++mt) {
    const int pb = p0 + wm + mt * 16 + quad * 4;  // 4 consecutive p rows
    const float4 bias = *reinterpret_cast<const float4*>(b + pb);
    const float bb[4] = {bias.x, bias.y, bias.z, bias.w};
#pragma unroll
    for (int nt = 0; nt < 4; ++nt) {
      const int tc = t0 + wn + nt * 16 + l15;  // column t
      if (VLAY == 0) {
        ushort4 o;
        o.x = f2bf(acc[mt][nt][0] * SCL + bb[0]);
        o.y = f2bf(acc[mt][nt][1] * SCL + bb[1]);
        o.z = f2bf(acc[mt][nt][2] * SCL + bb[2]);
        o.w = f2bf(acc[mt][nt][3] * SCL + bb[3]);
        *reinterpret_cast<ushort4*>(y + ((size_t)n * TT + tc) * PP + pb) = o;
      } else {
#pragma unroll
        for (int r = 0; r < 4; ++r)
          y[((size_t)n * PP + pb + r) * TT + tc] = f2bf(acc[mt][nt][r] * SCL + bb[r]);
      }
    }
  }
}

// ---------------------------------------------------------------------------
// k_attn: one block per (n, g, 32 m-rows). MFMA QK^T -> LDS scores ->
// exact softmax -> MFMA AV. Q,K: [n][t][PP]; V: [n][p][TT]; SV: [n][t][PP].
// XCD-chunked swizzle (proven R3: FETCH 139->24.7 MB).
// NEW (R5): __launch_bounds__(256,2) unlocks the 256-VGPR budget (LDS
// already caps at 2 blocks/CU, so VGPRs to 256 are occupancy-free —
// VGPR_Count=88 proved the compiler was capping loads-in-flight at ~4-6);
// explicit 2-deep double-buffered QK (bkA/bkB, next pass's 16 loads issued
// before current pass's MFMAs -> counted vmcnt) and 4-deep rotating V
// prefetch in AV (~200cy lookahead ~= L2 hit latency).
// ---------------------------------------------------------------------------
__global__ __launch_bounds__(256, 2) void k_attn(
    const unsigned short* __restrict__ Q,
    const unsigned short* __restrict__ K,
    const unsigned short* __restrict__ V,
    unsigned short* __restrict__ SV) {
  __shared__ unsigned short Sc[32][1032];  // bf16 scores, row pad 8 (16B-aligned rows)
  __shared__ float rowinv[32];
  const int lin = blockIdx.x;
  const int wu  = (lin >> 3) | ((lin & 7) << 8);  // bijective: 2048 = 8 * 256
  const int m0 = (wu & 31) * 32;
  const int g  = (wu >> 5) & 3;
  const int n  = wu >> 7;
  const int tid  = threadIdx.x;
  const int wave = tid >> 6, lane = tid & 63;
  const int l15  = lane & 15, quad = lane >> 4;

  const unsigned short* Qn = Q + (size_t)n * TT * PP;
  const unsigned short* Kn = K + (size_t)n * TT * PP;
  const unsigned short* Vn = V + ((size_t)n * PP + g * DD) * TT;

  // Q a-frags: 2 m-tiles x 4 d-steps, resident across passes (32m x 128d)
  short8 aq[2][4];
#pragma unroll
  for (int mt = 0; mt < 2; ++mt)
#pragma unroll
    for (int ds = 0; ds < 4; ++ds)
      aq[mt][ds] = *reinterpret_cast<const short8*>(
          Qn + (size_t)(m0 + mt * 16 + l15) * PP + g * DD + ds * 32 + quad * 8);

  // ---- QK^T: 4 passes of 256 l, 2-deep double-buffered ----
  auto kload = [&](short8 (&dst)[4][4], int base_l) {
#pragma unroll
    for (int ds = 0; ds < 4; ++ds)
#pragma unroll
      for (int j = 0; j < 4; ++j)
        dst[ds][j] = *reinterpret_cast<const short8*>(
            Kn + (size_t)(base_l + (wave * 4 + j) * 16 + l15) * PP +
            g * DD + ds * 32 + quad * 8);
  };
  auto kcomp = [&](const short8 (&bk)[4][4], int base_l) {
    floatx4 acc[2][4] = {};
#pragma unroll
    for (int ds = 0; ds < 4; ++ds)
#pragma unroll
      for (int j = 0; j < 4; ++j) {
        acc[0][j] = MFMA(aq[0][ds], bk[ds][j], acc[0][j]);
        acc[1][j] = MFMA(aq[1][ds], bk[ds][j], acc[1][j]);
      }
#pragma unroll
    for (int mt = 0; mt < 2; ++mt)
#pragma unroll
      for (int j = 0; j < 4; ++j) {
        const int lc = base_l + (wave * 4 + j) * 16 + l15;
#pragma unroll
        for (int r = 0; r < 4; ++r)
          Sc[mt * 16 + quad * 4 + r][lc] = f2bf(acc[mt][j][r] * SCL);
      }
  };

  short8 bkA[4][4], bkB[4][4];
  kload(bkA, 0);
  kload(bkB, 256);      // 32 loads in flight
  kcomp(bkA, 0);        // waits vmcnt(16): only pass-0 loads
  kload(bkA, 512);
  kcomp(bkB, 256);
  kload(bkB, 768);
  kcomp(bkA, 512);
  kcomp(bkB, 768);
  __syncthreads();

  // ---- exact softmax: 8 lanes per row, INTERLEAVED 16B chunks ----
  // (conflict-free: an 8-lane row-group covers 128 contiguous bytes/iter)
  {
    const int mi = tid >> 3;
    const int j  = tid & 7;
    unsigned short* row = &Sc[mi][0];
    float mx = -1e30f;
#pragma unroll
    for (int i = 0; i < 16; ++i) {
      short8 u = *reinterpret_cast<const short8*>(&row[(i * 8 + j) * 8]);
      float a0 = fmaxf(bf2f((unsigned short)u[0]), bf2f((unsigned short)u[1]));
      float a1 = fmaxf(bf2f((unsigned short)u[2]), bf2f((unsigned short)u[3]));
      float a2 = fmaxf(bf2f((unsigned short)u[4]), bf2f((unsigned short)u[5]));
      float a3 = fmaxf(bf2f((unsigned short)u[6]), bf2f((unsigned short)u[7]));
      mx = fmaxf(mx, fmaxf(fmaxf(a0, a1), fmaxf(a2, a3)));
    }
#pragma unroll
    for (int off = 4; off; off >>= 1) mx = fmaxf(mx, __shfl_xor(mx, off, 8));
    float sum = 0.f;
#pragma unroll
    for (int i = 0; i < 16; ++i) {
      short8 u = *reinterpret_cast<short8*>(&row[(i * 8 + j) * 8]);
      short8 o;
      float s0 = 0.f, s1 = 0.f;
#pragma unroll
      for (int e = 0; e < 8; e += 2) {
        float e0 = __expf(bf2f((unsigned short)u[e])     - mx);
        float e1 = __expf(bf2f((unsigned short)u[e + 1]) - mx);
        s0 += e0; s1 += e1;
        o[e]     = (short)f2bf(e0);
        o[e + 1] = (short)f2bf(e1);
      }
      sum += s0 + s1;
      *reinterpret_cast<short8*>(&row[(i * 8 + j) * 8]) = o;
    }
#pragma unroll
    for (int off = 4; off; off >>= 1) sum += __shfl_xor(sum, off, 8);
    if (j == 0) rowinv[mi] = 1.f / sum;
  }
  __syncthreads();

  // ---- AV: wave owns 32 d x 32 m; 1024 l in steps of 32, 4-deep V prefetch ----
  floatx4 av[2][2] = {};  // [d-tile][m-tile]
  auto vload = [&](short8 (&dst)[2], int ls) {
#pragma unroll
    for (int a = 0; a < 2; ++a)
      dst[a] = *reinterpret_cast<const short8*>(
          Vn + (size_t)(wave * 32 + a * 16 + l15) * TT + ls * 32 + quad * 8);
  };
  auto vstep = [&](const short8 (&va)[2], int ls) {
    short8 bp[2];
#pragma unroll
    for (int mt = 0; mt < 2; ++mt)
      bp[mt] = *reinterpret_cast<const short8*>(&Sc[mt * 16 + l15][ls * 32 + quad * 8]);
#pragma unroll
    for (int a = 0; a < 2; ++a)
#pragma unroll
      for (int mt = 0; mt < 2; ++mt)
        av[a][mt] = MFMA(va[a], bp[mt], av[a][mt]);
  };

  short8 va0[2], va1[2], va2[2], va3[2];
  vload(va0, 0); vload(va1, 1); vload(va2, 2); vload(va3, 3);
#pragma unroll
  for (int ls = 0; ls < 32; ls += 4) {
    vstep(va0, ls);     if (ls + 4 < 32) vload(va0, ls + 4);
    vstep(va1, ls + 1); if (ls + 5 < 32) vload(va1, ls + 5);
    vstep(va2, ls + 2); if (ls + 6 < 32) vload(va2, ls + 6);
    vstep(va3, ls + 3); if (ls + 7 < 32) vload(va3, ls + 7);
  }

#pragma unroll
  for (int a = 0; a < 2; ++a) {
    const int pb = g * DD + wave * 32 + a * 16 + quad * 4;  // 4 consecutive planes
#pragma unroll
    for (int mt = 0; mt < 2; ++mt) {
      const float inv = rowinv[mt * 16 + l15];  // D cols = m
      ushort4 o;
      o.x = f2bf(av[a][mt][0] * inv);
      o.y = f2bf(av[a][mt][1] * inv);
      o.z = f2bf(av[a][mt][2] * inv);
      o.w = f2bf(av[a][mt][3] * inv);
      *reinterpret_cast<ushort4*>(
          SV + ((size_t)n * TT + m0 + mt * 16 + l15) * PP + pb) = o;
    }
  }
}

// ---------------------------------------------------------------------------
// k_out: out[n][t][o] = SCL * sum_p SV[t][p] * w[o][p] + b[o]   (fp32 out)
//   A = proj_w (OO x PP fp32), B = SV (TT x PP bf16, p-contiguous).
// 128(o) x 128(t) tile, same skeleton as k_proj. Plain grid (R2-verified;
// the R3 XCD swizzle thrashed L2: proj_w 4MB + SV slice 2MB > 4MB).
// ---------------------------------------------------------------------------
__global__ __launch_bounds__(256) void k_out(
    const unsigned short* __restrict__ SVp, const float* __restrict__ w,
    const float* __restrict__ b, float* __restrict__ out) {
  __shared__ unsigned short Wt[128][32];  // [o][p] bf16
  __shared__ unsigned short St[128][32];  // [t][p] bf16
  const int n  = blockIdx.z;
  const int o0 = blockIdx.y * 128;
  const int t0 = blockIdx.x * 128;
  const int tid  = threadIdx.x;
  const int wave = tid >> 6, lane = tid & 63;
  const int l15  = lane & 15, quad = lane >> 4;
  const int wm = (wave >> 1) * 64, wn = (wave & 1) * 64;
  const int srow = tid >> 3, scol = (tid & 7) * 4;
  const unsigned short* SVn = SVp + (size_t)n * TT * PP;
  floatx4 acc[4][4] = {};

  for (int k0 = 0; k0 < PP; k0 += 32) {
    float4 awf[4];
    ushort4 us[4];
#pragma unroll
    for (int q = 0; q < 4; ++q) {
      awf[q] = *reinterpret_cast<const float4*>(w + (size_t)(o0 + srow + q * 32) * PP + k0 + scol);
      us[q]  = *reinterpret_cast<const ushort4*>(SVn + (size_t)(t0 + srow + q * 32) * PP + k0 + scol);
    }
    __syncthreads();
#pragma unroll
    for (int q = 0; q < 4; ++q) {
      *reinterpret_cast<ushort4*>(&Wt[srow + q * 32][scol]) = pack4(awf[q]);
      *reinterpret_cast<ushort4*>(&St[srow + q * 32][scol]) = us[q];
    }
    __syncthreads();
    short8 af[4], bs[4];
#pragma unroll
    for (int mt = 0; mt < 4; ++mt)
      af[mt] = *reinterpret_cast<const short8*>(&Wt[wm + mt * 16 + l15][quad * 8]);
#pragma unroll
    for (int nt = 0; nt < 4; ++nt)
      bs[nt] = *reinterpret_cast<const short8*>(&St[wn + nt * 16 + l15][quad * 8]);
#pragma unroll
    for (int mt = 0; mt < 4; ++mt)
#pragma unroll
      for (int nt = 0; nt < 4; ++nt)
        acc[mt][nt] = MFMA(af[mt], bs[nt], acc[mt][nt]);
  }

#pragma unroll
  for (int mt = 0; mt < 4; ++mt) {
    const int ob = o0 + wm + mt * 16 + quad * 4;  // 4 consecutive o
    const float4 bias = *reinterpret_cast<const float4*>(b + ob);
    const float bb[4] = {bias.x, bias.y, bias.z, bias.w};
#pragma unroll
    for (int nt = 0; nt < 4; ++nt) {
      const int tc = t0 + wn + nt * 16 + l15;
      float4 o;
      o.x = acc[mt][nt][0] * SCL + bb[0];
      o.y = acc[mt][nt][1] * SCL + bb[1];
      o.z = acc[mt][nt][2] * SCL + bb[2];
      o.w = acc[mt][nt][3] * SCL + bb[3];
      *reinterpret_cast<float4*>(out + ((size_t)n * TT + tc) * OO + ob) = o;
    }
  }
}

// ---------------------------------------------------------------------------
// Buffers: inputs/outputs are fp32. d_out is 128 MB fp32; Q/K/V bf16
// scratch (16 MB each) live at its head and are dead before k_out writes.
// SV (16 MB bf16) lives in d_ws (survives while out is written).
// ---------------------------------------------------------------------------
extern "C" void kernel_launch(void* const* d_in, const int* in_sizes, int n_in,
                              void* d_out, int out_size, void* d_ws, size_t ws_size,
                              hipStream_t stream) {
  (void)in_sizes; (void)n_in; (void)out_size; (void)ws_size;
  const float* attention = (const float*)d_in[0];  // (16,1024,512)
  const float* op_param  = (const float*)d_in[1];  // (16,1024,512)
  const float* q_w = (const float*)d_in[2];        // (512,512)
  const float* q_b = (const float*)d_in[3];        // (512)
  const float* k_w = (const float*)d_in[4];
  const float* k_b = (const float*)d_in[5];
  const float* v_w = (const float*)d_in[6];
  const float* v_b = (const float*)d_in[7];
  const float* proj_w = (const float*)d_in[8];     // (2048,512)
  const float* proj_b = (const float*)d_in[9];     // (2048)
  float* out = (float*)d_out;                      // (16,1024,2048) fp32 = 128 MB

  const size_t NPT = (size_t)NB * PP * TT;         // 8,388,608 elems = 16 MB bf16
  unsigned short* scratch = (unsigned short*)d_out;
  unsigned short* Qw  = scratch;            // [n][t][PP]
  unsigned short* Kw  = scratch + NPT;      // [n][t][PP]
  unsigned short* Vw  = scratch + 2 * NPT;  // [n][p][TT]
  unsigned short* SVw = (unsigned short*)d_ws;  // [n][t][PP]

  dim3 blk(256);
  dim3 gp(TT / 128, PP / 128, NB);                 // (8, 4, 16)
  k_proj<0><<<gp, blk, 0, stream>>>(op_param,  q_w, q_b, Qw);
  k_proj<0><<<gp, blk, 0, stream>>>(attention, k_w, k_b, Kw);
  k_proj<1><<<gp, blk, 0, stream>>>(attention, v_w, v_b, Vw);
  k_attn<<<dim3(2048), blk, 0, stream>>>(Qw, Kw, Vw, SVw);              // XCD-chunked
  k_out<<<dim3(TT / 128, OO / 128, NB), blk, 0, stream>>>(SVw, proj_w, proj_b, out);
}

// Round 6
// 418.264 us; speedup vs baseline: 1.1222x; 1.0688x over previous
//
#include <hip/hip_runtime.h>
#include <hip/hip_bf16.h>

// Problem constants (fixed by the reference)
#define NB 16     // batch N
#define TT 1024   // L == M
#define CC 512    // IN_DIM == PARAM_DIM
#define PP 512    // PLANES
#define GG 4      // GROUPS
#define DD 128    // GROUP_PLANES
#define OO 2048   // OUT_DIM

#define SCL 0.04419417382415922f  // 1/sqrt(512): equal_linear scale AND attn scale

typedef __attribute__((ext_vector_type(8))) short short8;   // 8 bf16 (4 VGPRs)
typedef __attribute__((ext_vector_type(4))) float floatx4;  // 4 fp32 acc
#define MFMA(a, b, c) __builtin_amdgcn_mfma_f32_16x16x32_bf16((a), (b), (c), 0, 0, 0)

static __device__ __forceinline__ float bf2f(unsigned short u) {
  union { unsigned int i; float f; } v; v.i = ((unsigned int)u) << 16; return v.f;
}
// Manual RNE bit-round (R2-verified). __float2bfloat16 was the R4 regressor:
// +31 us across the conversion-dense proj/out staging paths (NaN-checking
// software sequence, not a bare v_cvt). Do not "upgrade" this again.
static __device__ __forceinline__ unsigned short f2bf(float f) {
  union { float f; unsigned int i; } v; v.f = f;
  unsigned int r = (v.i + 0x7fffu + ((v.i >> 16) & 1u)) >> 16;
  return (unsigned short)r;
}
static __device__ __forceinline__ ushort4 pack4(float4 v) {
  ushort4 o; o.x = f2bf(v.x); o.y = f2bf(v.y); o.z = f2bf(v.z); o.w = f2bf(v.w); return o;
}

// ---------------------------------------------------------------------------
// k_proj<VLAY>: D[p][t] = SCL * (w[p][:] . x[n][t][:]) + b[p]
//   A = w (PP x CC fp32), B = x (TT x CC fp32 per n) — both k-contiguous.
//   VLAY==0: y[n][t][PP]  (Q/K: d-contiguous for QK^T operands)
//   VLAY==1: y[n][PP][t]  (V: l-contiguous for AV A-operand)
// 128x128 block tile, 4 waves (2x2), wave 64x64 = 4x4 MFMA tiles, BK=32.
// (R2-verified shape; R4 fusion reverted, manual f2bf restored.)
// ---------------------------------------------------------------------------
template <int VLAY>
__global__ __launch_bounds__(256) void k_proj(
    const float* __restrict__ x, const float* __restrict__ w,
    const float* __restrict__ b, unsigned short* __restrict__ y) {
  __shared__ unsigned short Aw[128][32];  // [p][k] bf16
  __shared__ unsigned short Xw[128][32];  // [t][k] bf16
  const int n  = blockIdx.z;
  const int p0 = blockIdx.y * 128;
  const int t0 = blockIdx.x * 128;
  const int tid  = threadIdx.x;
  const int wave = tid >> 6, lane = tid & 63;
  const int l15  = lane & 15, quad = lane >> 4;
  const int wm = (wave >> 1) * 64, wn = (wave & 1) * 64;
  const int srow = tid >> 3, scol = (tid & 7) * 4;  // staging: 8 thr/row of 32
  const float* xn = x + (size_t)n * TT * CC;
  floatx4 acc[4][4] = {};

  for (int k0 = 0; k0 < CC; k0 += 32) {
    float4 aw[4], ax[4];
#pragma unroll
    for (int q = 0; q < 4; ++q) {
      aw[q] = *reinterpret_cast<const float4*>(w  + (size_t)(p0 + srow + q * 32) * CC + k0 + scol);
      ax[q] = *reinterpret_cast<const float4*>(xn + (size_t)(t0 + srow + q * 32) * CC + k0 + scol);
    }
    __syncthreads();  // previous tile consumed
#pragma unroll
    for (int q = 0; q < 4; ++q) {
      *reinterpret_cast<ushort4*>(&Aw[srow + q * 32][scol]) = pack4(aw[q]);
      *reinterpret_cast<ushort4*>(&Xw[srow + q * 32][scol]) = pack4(ax[q]);
    }
    __syncthreads();
    short8 af[4], bx[4];
#pragma unroll
    for (int mt = 0; mt < 4; ++mt)
      af[mt] = *reinterpret_cast<const short8*>(&Aw[wm + mt * 16 + l15][quad * 8]);
#pragma unroll
    for (int nt = 0; nt < 4; ++nt)
      bx[nt] = *reinterpret_cast<const short8*>(&Xw[wn + nt * 16 + l15][quad * 8]);
#pragma unroll
    for (int mt = 0; mt < 4; ++mt)
#pragma unroll
      for (int nt = 0; nt < 4; ++nt)
        acc[mt][nt] = MFMA(af[mt], bx[nt], acc[mt][nt]);
  }

#pragma unroll
  for (int mt = 0; mt < 4; ++mt) {
    const int pb = p0 + wm + mt * 16 + quad * 4;  // 4 consecutive p rows
    const float4 bias = *reinterpret_cast<const float4*>(b + pb);
    const float bb[4] = {bias.x, bias.y, bias.z, bias.w};
#pragma unroll
    for (int nt = 0; nt < 4; ++nt) {
      const int tc = t0 + wn + nt * 16 + l15;  // column t
      if (VLAY == 0) {
        ushort4 o;
        o.x = f2bf(acc[mt][nt][0] * SCL + bb[0]);
        o.y = f2bf(acc[mt][nt][1] * SCL + bb[1]);
        o.z = f2bf(acc[mt][nt][2] * SCL + bb[2]);
        o.w = f2bf(acc[mt][nt][3] * SCL + bb[3]);
        *reinterpret_cast<ushort4*>(y + ((size_t)n * TT + tc) * PP + pb) = o;
      } else {
#pragma unroll
        for (int r = 0; r < 4; ++r)
          y[((size_t)n * PP + pb + r) * TT + tc] = f2bf(acc[mt][nt][r] * SCL + bb[r]);
      }
    }
  }
}

// ---------------------------------------------------------------------------
// k_attn: one block per (n, g, 64 m-rows). 8 waves / 512 threads.
// m-tile 64 (was 32): each K-frag and V-frag now feeds 4 MFMAs (was 2) —
// per-wave global loads halve (QK 64->32 K-loads, AV 64->32 V-loads) with
// MFMA count unchanged. Compiler caps loads-in-flight regardless (VGPR=88
// at R5 despite explicit dbuf), so arithmetic intensity is the remaining
// latency lever. Sc[64][1032] = 129 KB LDS -> 1 block/CU, 8 waves =
// 2 waves/SIMD (same as before: 2 blocks x 4 waves).
// XCD-chunked swizzle kept (R3-proven): 1024 = 8 * 128; each XCD owns 128
// consecutive work-units = 2 complete n's.
// ---------------------------------------------------------------------------
__global__ __launch_bounds__(512, 2) void k_attn(
    const unsigned short* __restrict__ Q,
    const unsigned short* __restrict__ K,
    const unsigned short* __restrict__ V,
    unsigned short* __restrict__ SV) {
  __shared__ unsigned short Sc[64][1032];  // bf16 scores, row pad 8 (16B-aligned rows)
  __shared__ float rowinv[64];
  const int lin = blockIdx.x;
  const int wu  = (lin >> 3) | ((lin & 7) << 7);  // bijective: 1024 = 8 * 128
  const int m0 = (wu & 15) * 64;
  const int g  = (wu >> 4) & 3;
  const int n  = wu >> 6;
  const int tid  = threadIdx.x;
  const int wave = tid >> 6, lane = tid & 63;
  const int l15  = lane & 15, quad = lane >> 4;

  const unsigned short* Qn = Q + (size_t)n * TT * PP;
  const unsigned short* Kn = K + (size_t)n * TT * PP;
  const unsigned short* Vn = V + ((size_t)n * PP + g * DD) * TT;

  // Q a-frags: 4 m-tiles x 4 d-steps, resident across passes (64m x 128d)
  short8 aq[4][4];
#pragma unroll
  for (int mt = 0; mt < 4; ++mt)
#pragma unroll
    for (int ds = 0; ds < 4; ++ds)
      aq[mt][ds] = *reinterpret_cast<const short8*>(
          Qn + (size_t)(m0 + mt * 16 + l15) * PP + g * DD + ds * 32 + quad * 8);

  // ---- QK^T: 2 passes of 512 l; 8 waves x 4 l-tiles of 16 each ----
  auto kload = [&](short8 (&dst)[4][4], int base_l) {
#pragma unroll
    for (int ds = 0; ds < 4; ++ds)
#pragma unroll
      for (int j = 0; j < 4; ++j)
        dst[ds][j] = *reinterpret_cast<const short8*>(
            Kn + (size_t)(base_l + (wave * 4 + j) * 16 + l15) * PP +
            g * DD + ds * 32 + quad * 8);
  };
  auto kcomp = [&](const short8 (&bk)[4][4], int base_l) {
    floatx4 acc[4][4] = {};  // [m-tile][j]
#pragma unroll
    for (int ds = 0; ds < 4; ++ds)
#pragma unroll
      for (int j = 0; j < 4; ++j)
#pragma unroll
        for (int mt = 0; mt < 4; ++mt)
          acc[mt][j] = MFMA(aq[mt][ds], bk[ds][j], acc[mt][j]);
#pragma unroll
    for (int mt = 0; mt < 4; ++mt)
#pragma unroll
      for (int j = 0; j < 4; ++j) {
        const int lc = base_l + (wave * 4 + j) * 16 + l15;
#pragma unroll
        for (int r = 0; r < 4; ++r)
          Sc[mt * 16 + quad * 4 + r][lc] = f2bf(acc[mt][j][r] * SCL);
      }
  };

  short8 bkA[4][4], bkB[4][4];
  kload(bkA, 0);
  kload(bkB, 512);
  kcomp(bkA, 0);
  kcomp(bkB, 512);
  __syncthreads();

  // ---- exact softmax: 8 lanes per row, INTERLEAVED 16B chunks ----
  // (conflict-free: an 8-lane row-group covers 128 contiguous bytes/iter)
  {
    const int mi = tid >> 3;   // 512 threads / 8 = 64 rows
    const int j  = tid & 7;
    unsigned short* row = &Sc[mi][0];
    float mx = -1e30f;
#pragma unroll
    for (int i = 0; i < 16; ++i) {
      short8 u = *reinterpret_cast<const short8*>(&row[(i * 8 + j) * 8]);
      float a0 = fmaxf(bf2f((unsigned short)u[0]), bf2f((unsigned short)u[1]));
      float a1 = fmaxf(bf2f((unsigned short)u[2]), bf2f((unsigned short)u[3]));
      float a2 = fmaxf(bf2f((unsigned short)u[4]), bf2f((unsigned short)u[5]));
      float a3 = fmaxf(bf2f((unsigned short)u[6]), bf2f((unsigned short)u[7]));
      mx = fmaxf(mx, fmaxf(fmaxf(a0, a1), fmaxf(a2, a3)));
    }
#pragma unroll
    for (int off = 4; off; off >>= 1) mx = fmaxf(mx, __shfl_xor(mx, off, 8));
    float sum = 0.f;
#pragma unroll
    for (int i = 0; i < 16; ++i) {
      short8 u = *reinterpret_cast<short8*>(&row[(i * 8 + j) * 8]);
      short8 o;
      float s0 = 0.f, s1 = 0.f;
#pragma unroll
      for (int e = 0; e < 8; e += 2) {
        float e0 = __expf(bf2f((unsigned short)u[e])     - mx);
        float e1 = __expf(bf2f((unsigned short)u[e + 1]) - mx);
        s0 += e0; s1 += e1;
        o[e]     = (short)f2bf(e0);
        o[e + 1] = (short)f2bf(e1);
      }
      sum += s0 + s1;
      *reinterpret_cast<short8*>(&row[(i * 8 + j) * 8]) = o;
    }
#pragma unroll
    for (int off = 4; off; off >>= 1) sum += __shfl_xor(sum, off, 8);
    if (j == 0) rowinv[mi] = 1.f / sum;
  }
  __syncthreads();

  // ---- AV: wave owns 16 d (1 d-tile) x 64 m (4 m-tiles); 1024 l in
  // steps of 32, 4-deep rotating V prefetch (~200cy lookahead). Each V
  // frag feeds 4 MFMAs. ----
  floatx4 av[4] = {};  // [m-tile]
  auto vload = [&](int ls) {
    return *reinterpret_cast<const short8*>(
        Vn + (size_t)(wave * 16 + l15) * TT + ls * 32 + quad * 8);
  };
  auto vstep = [&](short8 va, int ls) {
#pragma unroll
    for (int mt = 0; mt < 4; ++mt) {
      short8 bp = *reinterpret_cast<const short8*>(&Sc[mt * 16 + l15][ls * 32 + quad * 8]);
      av[mt] = MFMA(va, bp, av[mt]);
    }
  };

  short8 va0 = vload(0), va1 = vload(1), va2 = vload(2), va3 = vload(3);
#pragma unroll
  for (int ls = 0; ls < 32; ls += 4) {
    vstep(va0, ls);     if (ls + 4 < 32) va0 = vload(ls + 4);
    vstep(va1, ls + 1); if (ls + 5 < 32) va1 = vload(ls + 5);
    vstep(va2, ls + 2); if (ls + 6 < 32) va2 = vload(ls + 6);
    vstep(va3, ls + 3); if (ls + 7 < 32) va3 = vload(ls + 7);
  }

  const int pb = g * DD + wave * 16 + quad * 4;  // 4 consecutive planes
#pragma unroll
  for (int mt = 0; mt < 4; ++mt) {
    const float inv = rowinv[mt * 16 + l15];  // D cols = m
    ushort4 o;
    o.x = f2bf(av[mt][0] * inv);
    o.y = f2bf(av[mt][1] * inv);
    o.z = f2bf(av[mt][2] * inv);
    o.w = f2bf(av[mt][3] * inv);
    *reinterpret_cast<ushort4*>(
        SV + ((size_t)n * TT + m0 + mt * 16 + l15) * PP + pb) = o;
  }
}

// ---------------------------------------------------------------------------
// k_out: out[n][t][o] = SCL * sum_p SV[t][p] * w[o][p] + b[o]   (fp32 out)
//   A = proj_w (OO x PP fp32), B = SV (TT x PP bf16, p-contiguous).
// 128(o) x 128(t) tile, same skeleton as k_proj. Plain grid (R2-verified;
// the R3 XCD swizzle thrashed L2: proj_w 4MB + SV slice 2MB > 4MB).
// ---------------------------------------------------------------------------
__global__ __launch_bounds__(256) void k_out(
    const unsigned short* __restrict__ SVp, const float* __restrict__ w,
    const float* __restrict__ b, float* __restrict__ out) {
  __shared__ unsigned short Wt[128][32];  // [o][p] bf16
  __shared__ unsigned short St[128][32];  // [t][p] bf16
  const int n  = blockIdx.z;
  const int o0 = blockIdx.y * 128;
  const int t0 = blockIdx.x * 128;
  const int tid  = threadIdx.x;
  const int wave = tid >> 6, lane = tid & 63;
  const int l15  = lane & 15, quad = lane >> 4;
  const int wm = (wave >> 1) * 64, wn = (wave & 1) * 64;
  const int srow = tid >> 3, scol = (tid & 7) * 4;
  const unsigned short* SVn = SVp + (size_t)n * TT * PP;
  floatx4 acc[4][4] = {};

  for (int k0 = 0; k0 < PP; k0 += 32) {
    float4 awf[4];
    ushort4 us[4];
#pragma unroll
    for (int q = 0; q < 4; ++q) {
      awf[q] = *reinterpret_cast<const float4*>(w + (size_t)(o0 + srow + q * 32) * PP + k0 + scol);
      us[q]  = *reinterpret_cast<const ushort4*>(SVn + (size_t)(t0 + srow + q * 32) * PP + k0 + scol);
    }
    __syncthreads();
#pragma unroll
    for (int q = 0; q < 4; ++q) {
      *reinterpret_cast<ushort4*>(&Wt[srow + q * 32][scol]) = pack4(awf[q]);
      *reinterpret_cast<ushort4*>(&St[srow + q * 32][scol]) = us[q];
    }
    __syncthreads();
    short8 af[4], bs[4];
#pragma unroll
    for (int mt = 0; mt < 4; ++mt)
      af[mt] = *reinterpret_cast<const short8*>(&Wt[wm + mt * 16 + l15][quad * 8]);
#pragma unroll
    for (int nt = 0; nt < 4; ++nt)
      bs[nt] = *reinterpret_cast<const short8*>(&St[wn + nt * 16 + l15][quad * 8]);
#pragma unroll
    for (int mt = 0; mt < 4; ++mt)
#pragma unroll
      for (int nt = 0; nt < 4; ++nt)
        acc[mt][nt] = MFMA(af[mt], bs[nt], acc[mt][nt]);
  }

#pragma unroll
  for (int mt = 0; mt < 4; ++mt) {
    const int ob = o0 + wm + mt * 16 + quad * 4;  // 4 consecutive o
    const float4 bias = *reinterpret_cast<const float4*>(b + ob);
    const float bb[4] = {bias.x, bias.y, bias.z, bias.w};
#pragma unroll
    for (int nt = 0; nt < 4; ++nt) {
      const int tc = t0 + wn + nt * 16 + l15;
      float4 o;
      o.x = acc[mt][nt][0] * SCL + bb[0];
      o.y = acc[mt][nt][1] * SCL + bb[1];
      o.z = acc[mt][nt][2] * SCL + bb[2];
      o.w = acc[mt][nt][3] * SCL + bb[3];
      *reinterpret_cast<float4*>(out + ((size_t)n * TT + tc) * OO + ob) = o;
    }
  }
}

// ---------------------------------------------------------------------------
// Buffers: inputs/outputs are fp32. d_out is 128 MB fp32; Q/K/V bf16
// scratch (16 MB each) live at its head and are dead before k_out writes.
// SV (16 MB bf16) lives in d_ws (survives while out is written).
// ---------------------------------------------------------------------------
extern "C" void kernel_launch(void* const* d_in, const int* in_sizes, int n_in,
                              void* d_out, int out_size, void* d_ws, size_t ws_size,
                              hipStream_t stream) {
  (void)in_sizes; (void)n_in; (void)out_size; (void)ws_size;
  const float* attention = (const float*)d_in[0];  // (16,1024,512)
  const float* op_param  = (const float*)d_in[1];  // (16,1024,512)
  const float* q_w = (const float*)d_in[2];        // (512,512)
  const float* q_b = (const float*)d_in[3];        // (512)
  const float* k_w = (const float*)d_in[4];
  const float* k_b = (const float*)d_in[5];
  const float* v_w = (const float*)d_in[6];
  const float* v_b = (const float*)d_in[7];
  const float* proj_w = (const float*)d_in[8];     // (2048,512)
  const float* proj_b = (const float*)d_in[9];     // (2048)
  float* out = (float*)d_out;                      // (16,1024,2048) fp32 = 128 MB

  const size_t NPT = (size_t)NB * PP * TT;         // 8,388,608 elems = 16 MB bf16
  unsigned short* scratch = (unsigned short*)d_out;
  unsigned short* Qw  = scratch;            // [n][t][PP]
  unsigned short* Kw  = scratch + NPT;      // [n][t][PP]
  unsigned short* Vw  = scratch + 2 * NPT;  // [n][p][TT]
  unsigned short* SVw = (unsigned short*)d_ws;  // [n][t][PP]

  dim3 blk(256);
  dim3 gp(TT / 128, PP / 128, NB);                 // (8, 4, 16)
  k_proj<0><<<gp, blk, 0, stream>>>(op_param,  q_w, q_b, Qw);
  k_proj<0><<<gp, blk, 0, stream>>>(attention, k_w, k_b, Kw);
  k_proj<1><<<gp, blk, 0, stream>>>(attention, v_w, v_b, Vw);
  k_attn<<<dim3(1024), dim3(512), 0, stream>>>(Qw, Kw, Vw, SVw);        // XCD-chunked
  k_out<<<dim3(TT / 128, OO / 128, NB), blk, 0, stream>>>(SVw, proj_w, proj_b, out);
}